// Round 2
// baseline (403.687 us; speedup 1.0000x reference)
//
#include <hip/hip_runtime.h>
#include <hip/hip_bf16.h>
#include <stdint.h>

#define HF 256   // H == F == 256
#define GG 50    // G

typedef __attribute__((ext_vector_type(8))) short bf16x8;
typedef __attribute__((ext_vector_type(4))) short bf16x4;
typedef __attribute__((ext_vector_type(4))) float f32x4;
typedef float f32x4a __attribute__((ext_vector_type(4), aligned(4)));  // dword-aligned vec4 load

// packed f32x2 -> bf16x2 (v_cvt_pk_bf16_f32 on gfx950), low short = a
__device__ __forceinline__ uint32_t f2bf2u(float a, float b){
    __hip_bfloat162 h = __float22bfloat162_rn(make_float2(a, b));
    union { __hip_bfloat162 h; uint32_t u; } v; v.h = h; return v.u;
}
__device__ __forceinline__ float bf2f(short s){
    union { uint32_t u; float f; } v; v.u = ((uint32_t)(uint16_t)s) << 16;
    return v.f;
}
// shifted softplus: ln(1+e^x) - ln2 (safe for |x| < ~80; GEMM outputs are O(+-6))
__device__ __forceinline__ float ssp_f(float x){
    float e = __builtin_amdgcn_exp2f(x * 1.44269504088896341f);
    return 0.69314718055994531f * __builtin_amdgcn_logf(1.0f + e)
         - 0.69314718055994531f;
}

// ---------------------------------------------------------------------------
// prep_kernel: [pack weights] + [x fp32->bf16] + [degree histogram] + [agg=0]
// B-frag (ntg, kt): lane l holds B[k=kt*32+(l>>4)*8+j][n=ntg*16+(l&15)].
// pi(s) = (s>>6)*64 + (s&3)*16 + ((s&63)>>2)  (hidden-feature storage perm)
// w1p: bias b1 folded in as constant-1 row k=50 (zero-pad region of K=64).
// ---------------------------------------------------------------------------
__device__ __forceinline__ void pack_natural(const float* __restrict__ B,
                                             short* __restrict__ Bp,
                                             int idx, int KT, int kmax)
{
    int lane = idx & 63;
    int kt   = (idx >> 6) & (KT - 1);
    int ntg  = idx >> (6 + (KT == 2 ? 1 : 3));
    int col  = ntg * 16 + (lane & 15);
    int k0   = kt * 32 + (lane >> 4) * 8;
    uint32_t u[4];
#pragma unroll
    for (int jj = 0; jj < 4; ++jj) {
        int ka = k0 + 2*jj, kb = ka + 1;
        float a = (ka < kmax) ? B[(size_t)ka * HF + col] : 0.f;
        float b = (kb < kmax) ? B[(size_t)kb * HF + col] : 0.f;
        u[jj] = f2bf2u(a, b);
    }
    *(uint4*)&Bp[(size_t)idx * 8] = *(uint4*)u;
}

__global__ __launch_bounds__(256)
void prep_kernel(const float* __restrict__ w1, const float* __restrict__ b1,
                 const float* __restrict__ w2,
                 const float* __restrict__ lin1, const float* __restrict__ lin2,
                 short* __restrict__ w1p, short* __restrict__ w2p,
                 short* __restrict__ lin1p, short* __restrict__ lin2p,
                 const float* __restrict__ x, short* __restrict__ x_bf, int nx8,
                 const int* __restrict__ eidx, int* __restrict__ cnt, int E,
                 float* __restrict__ agg, int nAgg4, int gConv, int gHist)
{
    int b = blockIdx.x, tid = threadIdx.x;
    if (b < 8) {                       // w1p with b1 folded at k==GG
        int idx  = b * 256 + tid;
        int lane = idx & 63;
        int kt   = (idx >> 6) & 1;
        int ntg  = idx >> 7;
        int col  = ntg * 16 + (lane & 15);
        int k0   = kt * 32 + (lane >> 4) * 8;
        uint32_t u[4];
#pragma unroll
        for (int jj = 0; jj < 4; ++jj) {
            int ka = k0 + 2*jj, kb = ka + 1;
            float va = (ka < GG) ? w1[(size_t)ka * HF + col]
                                 : ((ka == GG) ? b1[col] : 0.f);
            float vb = (kb < GG) ? w1[(size_t)kb * HF + col]
                                 : ((kb == GG) ? b1[col] : 0.f);
            u[jj] = f2bf2u(va, vb);
        }
        *(uint4*)&w1p[(size_t)idx * 8] = *(uint4*)u;
    } else if (b < 40) {               // w2p: permuted k axis
        int idx = (b - 8) * 256 + tid;
        int lane = idx & 63;
        int kt   = (idx >> 6) & 7;
        int ntg  = idx >> 9;
        int col  = ntg * 16 + (lane & 15);
        int s0   = kt * 32 + (lane >> 4) * 8;
        uint32_t u[4];
#pragma unroll
        for (int jj = 0; jj < 4; ++jj) {
            int sa = s0 + 2*jj, sb = sa + 1;
            int fa = (sa >> 6) * 64 + (sa & 3) * 16 + ((sa & 63) >> 2);
            int fb = (sb >> 6) * 64 + (sb & 3) * 16 + ((sb & 63) >> 2);
            u[jj] = f2bf2u(w2[(size_t)fa * HF + col], w2[(size_t)fb * HF + col]);
        }
        *(uint4*)&w2p[(size_t)idx * 8] = *(uint4*)u;
    } else if (b < 72) {
        pack_natural(lin1, lin1p, (b - 40) * 256 + tid, 8, HF);
    } else if (b < 104) {
        pack_natural(lin2, lin2p, (b - 72) * 256 + tid, 8, HF);
    } else if (b < 104 + gConv) {      // x -> bf16, 8 elems/thread
        int idx = (b - 104) * 256 + tid;
        if (idx < nx8) {
            const float* xp = x + (size_t)idx * 8;
            float4 p0 = *(const float4*)(xp);
            float4 p1 = *(const float4*)(xp + 4);
            uint32_t u[4] = { f2bf2u(p0.x, p0.y), f2bf2u(p0.z, p0.w),
                              f2bf2u(p1.x, p1.y), f2bf2u(p1.z, p1.w) };
            *(uint4*)&x_bf[(size_t)idx * 8] = *(uint4*)u;
        }
    } else if (b < 104 + gConv + gHist) {   // histogram
        int e = (b - 104 - gConv) * 256 + tid;
        if (e < E) atomicAdd(&cnt[eidx[e]], 1);
    } else {                           // agg zero (float4 granular)
        int idx = (b - 104 - gConv - gHist) * 256 + tid;
        if (idx < nAgg4) ((float4*)agg)[idx] = make_float4(0.f, 0.f, 0.f, 0.f);
    }
}

// ---------------------------------------------------------------------------
// gemm_scan_kernel: blocks [0, gNode) do the y_p GEMM (M-tile 32);
// block gNode runs the 1-block exclusive scan CONCURRENTLY (hides its serial
// latency under the GEMM instead of a dedicated launch).
// ---------------------------------------------------------------------------
__global__ __launch_bounds__(256)
void gemm_scan_kernel(const short* __restrict__ x_bf, const short* __restrict__ lin1p,
                      short* __restrict__ y_p, int N,
                      const int* __restrict__ cnt, int* __restrict__ row,
                      int* __restrict__ cursor, int E, int gNode)
{
    const int tid = threadIdx.x;
    if ((int)blockIdx.x >= gNode) {    // ---- scan block
        __shared__ int part[256];
        const int CH = (N + 255) / 256;
        int lo = tid * CH;
        int hi = min(lo + CH, N);
        int s = 0;
        for (int n = lo; n < hi; ++n) s += cnt[n];
        part[tid] = s;
        __syncthreads();
        for (int off = 1; off < 256; off <<= 1) {
            int v = (tid >= off) ? part[tid - off] : 0;
            __syncthreads();
            part[tid] += v;
            __syncthreads();
        }
        int acc = part[tid] - s;   // exclusive
        for (int n = lo; n < hi; ++n) {
            row[n] = acc; cursor[n] = acc;
            acc += cnt[n];
        }
        if (tid == 255) row[N] = E;
        return;
    }
    // ---- y_p GEMM
    const int lane = tid & 63;
    const int w    = tid >> 6;
    const int l15  = lane & 15;
    const int quad = lane >> 4;
    const int row0 = blockIdx.x * 32;

    f32x4 acc[2][4];
#pragma unroll
    for (int mt = 0; mt < 2; ++mt)
#pragma unroll
        for (int nt = 0; nt < 4; ++nt) acc[mt][nt] = (f32x4){0.f,0.f,0.f,0.f};

#pragma unroll 2
    for (int kt = 0; kt < 8; ++kt) {
        bf16x8 af[2];
#pragma unroll
        for (int mt = 0; mt < 2; ++mt) {
            int r = row0 + mt * 16 + l15;
            int rl = (r < N) ? r : 0;
            af[mt] = *(const bf16x8*)&x_bf[(size_t)rl * HF + kt * 32 + quad * 8];
        }
#pragma unroll
        for (int nt = 0; nt < 4; ++nt) {
            bf16x8 bfr = *(const bf16x8*)&lin1p[(size_t)(((w*4+nt)*8+kt)*64+lane)*8];
#pragma unroll
            for (int mt = 0; mt < 2; ++mt)
                acc[mt][nt] = __builtin_amdgcn_mfma_f32_16x16x32_bf16(af[mt], bfr, acc[mt][nt], 0, 0, 0);
        }
    }
#pragma unroll
    for (int mt = 0; mt < 2; ++mt) {
#pragma unroll
        for (int r = 0; r < 4; ++r) {
            int row_ = row0 + mt * 16 + quad * 4 + r;
            if (row_ < N) {
                uint2 u = make_uint2(f2bf2u(acc[mt][0][r], acc[mt][1][r]),
                                     f2bf2u(acc[mt][2][r], acc[mt][3][r]));
                *(uint2*)&y_p[(size_t)row_ * HF + w * 64 + l15 * 4] = u;
            }
        }
    }
}

// ---------------------------------------------------------------------------
// scatter_kernel: counting-sort scatter using cursor from the scan
// ---------------------------------------------------------------------------
__global__ __launch_bounds__(256)
void scatter_kernel(const int* __restrict__ eidx, int* __restrict__ cursor,
                    int* __restrict__ perm, int E)
{
    int e = blockIdx.x * 256 + threadIdx.x;
    if (e < E) {
        int pos = atomicAdd(&cursor[eidx[e]], 1);
        perm[pos] = e;
    }
}

// ---------------------------------------------------------------------------
// node2_kernel: out = ssp(agg@lin2 + b) + x   (M-tile 32)
// ---------------------------------------------------------------------------
__global__ __launch_bounds__(256)
void node2_kernel(const float* __restrict__ agg, const short* __restrict__ lin2p,
                  const float* __restrict__ bias, const float* __restrict__ x,
                  float* __restrict__ out, int N)
{
    const int tid  = threadIdx.x;
    const int lane = tid & 63;
    const int w    = tid >> 6;
    const int l15  = lane & 15;
    const int quad = lane >> 4;
    const int row0 = blockIdx.x * 32;

    f32x4 acc[2][4];
#pragma unroll
    for (int mt = 0; mt < 2; ++mt)
#pragma unroll
        for (int nt = 0; nt < 4; ++nt) acc[mt][nt] = (f32x4){0.f,0.f,0.f,0.f};

#pragma unroll 2
    for (int kt = 0; kt < 8; ++kt) {
        bf16x8 af[2];
#pragma unroll
        for (int mt = 0; mt < 2; ++mt) {
            int r = row0 + mt * 16 + l15;
            int rl = (r < N) ? r : 0;
            const float* ap = agg + (size_t)rl * HF + kt * 32 + quad * 8;
            float4 p0 = *(const float4*)(ap);
            float4 p1 = *(const float4*)(ap + 4);
            union { uint32_t u[4]; bf16x8 v; } c;
            c.u[0] = f2bf2u(p0.x, p0.y); c.u[1] = f2bf2u(p0.z, p0.w);
            c.u[2] = f2bf2u(p1.x, p1.y); c.u[3] = f2bf2u(p1.z, p1.w);
            af[mt] = c.v;
        }
#pragma unroll
        for (int nt = 0; nt < 4; ++nt) {
            bf16x8 bfr = *(const bf16x8*)&lin2p[(size_t)(((w*4+nt)*8+kt)*64+lane)*8];
#pragma unroll
            for (int mt = 0; mt < 2; ++mt)
                acc[mt][nt] = __builtin_amdgcn_mfma_f32_16x16x32_bf16(af[mt], bfr, acc[mt][nt], 0, 0, 0);
        }
    }
    float bs[4];
#pragma unroll
    for (int nt = 0; nt < 4; ++nt) bs[nt] = bias[w * 64 + nt * 16 + l15];
#pragma unroll
    for (int mt = 0; mt < 2; ++mt) {
#pragma unroll
        for (int r = 0; r < 4; ++r) {
            int row_ = row0 + mt * 16 + quad * 4 + r;
            if (row_ < N) {
#pragma unroll
                for (int nt = 0; nt < 4; ++nt) {
                    int f = w * 64 + nt * 16 + l15;
                    float v = ssp_f(acc[mt][nt][r] + bs[nt]) + x[(size_t)row_ * HF + f];
                    out[(size_t)row_ * HF + f] = v;
                }
            }
        }
    }
}

// ---------------------------------------------------------------------------
// edge_mfma: per 64-sorted-edge block, 4 waves, wave w owns f-slice [64w,64w+64)
// 3-barrier structure:
//   [no barrier] per-wave metadata (redundant), GEMM1 A direct from fp32 ea
//   (bias row k=50 in-register), GEMM1, y_p gather issue, ssp->hid
//   barA: hid + runnode ready
//   GEMM2 (A from hid LDS, B = w2p)
//   barB: hid dead
//   msg epilogue -> msgT (aliases hid), St build (per-wave ballot mask)
//   barC
//   GEMM3 segment-sum (selection matrix), per-run flush (atomics only at
//   tile-boundary runs)
// LDS 39.2 KB -> 4 blocks/CU. St stride 72 (was 64: 16-way bank conflict).
// ---------------------------------------------------------------------------
__global__ __launch_bounds__(256, 4)
void edge_mfma(const float* __restrict__ ea, const int* __restrict__ eidx,
               const float* __restrict__ ew,
               const short* __restrict__ w1p,
               const short* __restrict__ w2p, const float* __restrict__ b2,
               const short* __restrict__ y_p, const int* __restrict__ perm,
               const int* __restrict__ rowp,
               float* __restrict__ agg, int E)
{
    __shared__ short smem[19584];      // 39168 B
    short* hid  = smem;                // [64][264] (phase 1-2: 33792 B)
    short* msgT = smem;                // [256][72] (phase 3+, aliases hid)
    short* St   = smem + 18432;        // [16][72]
    __shared__ int s_runnode[64];
    __shared__ unsigned char s_runcomp[64];

    const int tid  = threadIdx.x;
    const int lane = tid & 63;
    const int w    = tid >> 6;
    const int l15  = lane & 15;
    const int quad = lane >> 4;
    const int e0   = blockIdx.x * 64;

    // ---- per-wave metadata: lane holds edge (e0+lane)'s info; no barrier
    int pp = e0 + lane;
    int eL = 0, iv = -1;
    float c = 0.f;
    if (pp < E) {
        eL = perm[pp];
        iv = eidx[eL];
        float d0 = ew[eL*3+0], d1 = ew[eL*3+1], d2 = ew[eL*3+2];
        float d = sqrtf(d0*d0 + d1*d1 + d2*d2);
        c = (d <= 2.0f) ? 0.5f * (__cosf(d * 1.57079632679489662f) + 1.0f) : 0.f;
    }
    int jv = eidx[E + eL];
    int ivn = __shfl_down(iv, 1);
    bool flag = (lane == 63) || (iv != ivn);      // run ends at this lane
    unsigned long long bm = __ballot(flag);       // same value in every wave
    const int runcnt = (int)__popcll(bm);
    if (w == 0 && flag) {
        int rid = (int)__popcll(bm & ((1ull << lane) - 1ull));
        s_runnode[rid] = iv;
        int comp = 0;
        if (iv >= 0) {
            int lo = rowp[iv], hi = rowp[iv + 1];
            comp = (lo >= e0 && hi <= e0 + 64) ? 1 : 0;
        }
        s_runcomp[rid] = (unsigned char)comp;
    }

    // ---- GEMM1 A-fragments: direct dwordx4 loads from fp32 ea + cvt_pk.
    // k layout per fragment: k = kt*32 + quad*8 + j. Row k=50 is the folded
    // bias (constant 1.0), k>50 zero. quad==2/kt==1 covers k=48..55.
    int rp4[4];
#pragma unroll
    for (int mt = 0; mt < 4; ++mt) {
        int er = e0 + mt * 16 + l15;
        rp4[mt] = (er < E) ? perm[er] : 0;
    }
    bf16x8 a1[4][2];
#pragma unroll
    for (int mt = 0; mt < 4; ++mt) {
        const float* er = ea + (size_t)rp4[mt] * GG;
        f32x4a p0 = *(const f32x4a*)(er + quad * 8);
        f32x4a p1 = *(const f32x4a*)(er + quad * 8 + 4);
        union { uint32_t u[4]; bf16x8 v; } ca;
        ca.u[0] = f2bf2u(p0[0], p0[1]); ca.u[1] = f2bf2u(p0[2], p0[3]);
        ca.u[2] = f2bf2u(p1[0], p1[1]); ca.u[3] = f2bf2u(p1[2], p1[3]);
        a1[mt][0] = ca.v;
        union { uint32_t u[4]; bf16x8 v; } cb;
        if (quad < 2) {
            f32x4a q0 = *(const f32x4a*)(er + 32 + quad * 8);
            f32x4a q1 = *(const f32x4a*)(er + 36 + quad * 8);
            cb.u[0] = f2bf2u(q0[0], q0[1]); cb.u[1] = f2bf2u(q0[2], q0[3]);
            cb.u[2] = f2bf2u(q1[0], q1[1]); cb.u[3] = f2bf2u(q1[2], q1[3]);
        } else if (quad == 2) {
            float2 q = *(const float2*)(er + 48);
            cb.u[0] = f2bf2u(q.x, q.y);
            cb.u[1] = 0x00003F80u;      // k=50 -> 1.0 (bias row), k=51 -> 0
            cb.u[2] = 0u; cb.u[3] = 0u;
        } else {
            cb.u[0] = 0u; cb.u[1] = 0u; cb.u[2] = 0u; cb.u[3] = 0u;
        }
        a1[mt][1] = cb.v;
    }

    // ---- GEMM1: [64e x 64k] @ [64k x 64f-slice]
    f32x4 acc1[4][4];
#pragma unroll
    for (int mt = 0; mt < 4; ++mt)
#pragma unroll
        for (int nt = 0; nt < 4; ++nt) acc1[mt][nt] = (f32x4){0.f,0.f,0.f,0.f};
#pragma unroll
    for (int kt = 0; kt < 2; ++kt) {
#pragma unroll
        for (int nt = 0; nt < 4; ++nt) {
            bf16x8 bfr = *(const bf16x8*)&w1p[(size_t)(((w*4+nt)*2+kt)*64+lane)*8];
#pragma unroll
            for (int mt = 0; mt < 4; ++mt)
                acc1[mt][nt] = __builtin_amdgcn_mfma_f32_16x16x32_bf16(a1[mt][kt], bfr, acc1[mt][nt], 0, 0, 0);
        }
    }

    // ---- y_p gather: issue NOW (j via shfl of lane-local jv); consumed after
    // GEMM2 -> latency hides under ssp epilogue + barrier + GEMM2.
    bf16x4 yv[4][4];
#pragma unroll
    for (int mt = 0; mt < 4; ++mt)
#pragma unroll
        for (int r = 0; r < 4; ++r) {
            int j = __shfl(jv, mt * 16 + quad * 4 + r);
            yv[mt][r] = *(const bf16x4*)&y_p[(size_t)j * HF + w * 64 + l15 * 4];
        }

    // ssp -> hid (bf16, col' = w*64 + l15*4 + nt)
#pragma unroll
    for (int mt = 0; mt < 4; ++mt) {
#pragma unroll
        for (int r = 0; r < 4; ++r) {
            int e = mt * 16 + quad * 4 + r;
            float v0 = ssp_f(acc1[mt][0][r]);
            float v1 = ssp_f(acc1[mt][1][r]);
            float v2 = ssp_f(acc1[mt][2][r]);
            float v3 = ssp_f(acc1[mt][3][r]);
            uint2 u = make_uint2(f2bf2u(v0, v1), f2bf2u(v2, v3));
            *(uint2*)&hid[e * 264 + w * 64 + l15 * 4] = u;
        }
    }
    __syncthreads();   // barA: hid + runnode/runcomp ready

    // ---- GEMM2: [64e x 256k(perm)] @ [256k x 64f-slice]
    f32x4 acc2[4][4];
#pragma unroll
    for (int mt = 0; mt < 4; ++mt)
#pragma unroll
        for (int nt = 0; nt < 4; ++nt) acc2[mt][nt] = (f32x4){0.f,0.f,0.f,0.f};

#pragma unroll 2
    for (int kt = 0; kt < 8; ++kt) {
        bf16x8 af[4];
#pragma unroll
        for (int mt = 0; mt < 4; ++mt)
            af[mt] = *(bf16x8*)&hid[(mt * 16 + l15) * 264 + kt * 32 + quad * 8];
#pragma unroll
        for (int nt = 0; nt < 4; ++nt) {
            bf16x8 bfr = *(const bf16x8*)&w2p[(size_t)(((w*4+nt)*8+kt)*64+lane)*8];
#pragma unroll
            for (int mt = 0; mt < 4; ++mt)
                acc2[mt][nt] = __builtin_amdgcn_mfma_f32_16x16x32_bf16(af[mt], bfr, acc2[mt][nt], 0, 0, 0);
        }
    }
    __syncthreads();   // barB: hid dead; msgT/St may now overwrite

    // ---- msg epilogue -> msgT[col][e] (stride 72: 16B-aligned rows)
    float bias2[4];
#pragma unroll
    for (int nt = 0; nt < 4; ++nt) bias2[nt] = b2[w * 64 + nt * 16 + l15];
    float cs[4][4];
#pragma unroll
    for (int mt = 0; mt < 4; ++mt)
#pragma unroll
        for (int r = 0; r < 4; ++r)
            cs[mt][r] = __shfl(c, mt * 16 + quad * 4 + r);
#pragma unroll
    for (int mt = 0; mt < 4; ++mt) {
#pragma unroll
        for (int nt = 0; nt < 4; ++nt) {
            int col = w * 64 + nt * 16 + l15;
            float v0 = (acc2[mt][nt][0] + bias2[nt]) * cs[mt][0] * bf2f(yv[mt][0][nt]);
            float v1 = (acc2[mt][nt][1] + bias2[nt]) * cs[mt][1] * bf2f(yv[mt][1][nt]);
            float v2 = (acc2[mt][nt][2] + bias2[nt]) * cs[mt][2] * bf2f(yv[mt][2][nt]);
            float v3 = (acc2[mt][nt][3] + bias2[nt]) * cs[mt][3] * bf2f(yv[mt][3][nt]);
            uint2 u = make_uint2(f2bf2u(v0, v1), f2bf2u(v2, v3));
            *(uint2*)&msgT[col * 72 + mt * 16 + quad * 4] = u;
        }
    }
    // build S^T[run-local][edge] for run group 0 (stride 72 kills bank conflict)
    {
        int e   = tid & 63;
        int rb  = tid >> 6;
        int rid = (int)__popcll(bm & ((1ull << e) - 1ull));
#pragma unroll
        for (int q = 0; q < 4; ++q) {
            int r = rb + q * 4;
            St[r * 72 + e] = (rid == r) ? (short)0x3F80 : (short)0;
        }
    }
    __syncthreads();   // barC

    // ---- GEMM3: O[feature][run] = msgT @ S^T, then flush per run
    for (int ntg = 0; ntg * 16 < runcnt; ++ntg) {
        if (ntg > 0) {   // rare: >16 runs in a tile
            __syncthreads();
            int e   = tid & 63;
            int rb  = tid >> 6;
            int rid = (int)__popcll(bm & ((1ull << e) - 1ull));
#pragma unroll
            for (int q = 0; q < 4; ++q) {
                int r = rb + q * 4;
                St[r * 72 + e] = (rid == ntg * 16 + r) ? (short)0x3F80 : (short)0;
            }
            __syncthreads();
        }
        f32x4 acc3[4];
#pragma unroll
        for (int mt = 0; mt < 4; ++mt) acc3[mt] = (f32x4){0.f,0.f,0.f,0.f};
#pragma unroll
        for (int kt = 0; kt < 2; ++kt) {
            bf16x8 bS = *(bf16x8*)&St[l15 * 72 + kt * 32 + quad * 8];
#pragma unroll
            for (int mt = 0; mt < 4; ++mt) {
                bf16x8 af = *(bf16x8*)&msgT[(w*64 + mt*16 + l15) * 72 + kt*32 + quad*8];
                acc3[mt] = __builtin_amdgcn_mfma_f32_16x16x32_bf16(af, bS, acc3[mt], 0, 0, 0);
            }
        }
        // lane owns run r = ntg*16 + l15; features f = w*64 + mt*16 + quad*4 + g
        int r = ntg * 16 + l15;
        if (r < runcnt) {
            int node = s_runnode[r];
            if (node >= 0) {
                float* ap = agg + (size_t)node * HF + w * 64 + quad * 4;
                if (s_runcomp[r]) {
#pragma unroll
                    for (int mt = 0; mt < 4; ++mt) {
                        float4 v = make_float4(acc3[mt][0], acc3[mt][1], acc3[mt][2], acc3[mt][3]);
                        *(float4*)(ap + mt * 16) = v;
                    }
                } else {
#pragma unroll
                    for (int mt = 0; mt < 4; ++mt)
#pragma unroll
                        for (int g = 0; g < 4; ++g)
                            atomicAdd(ap + mt * 16 + g, acc3[mt][g]);
                }
            }
        }
    }
}

// ---------------------------------------------------------------------------
extern "C" void kernel_launch(void* const* d_in, const int* in_sizes, int n_in,
                              void* d_out, int out_size, void* d_ws, size_t ws_size,
                              hipStream_t stream)
{
    const float* x     = (const float*)d_in[0];
    const int*   eidx  = (const int*)  d_in[1];
    const float* ew    = (const float*)d_in[2];
    const float* ea    = (const float*)d_in[3];
    const float* w1    = (const float*)d_in[4];
    const float* b1    = (const float*)d_in[5];
    const float* w2    = (const float*)d_in[6];
    const float* b2    = (const float*)d_in[7];
    const float* lin1  = (const float*)d_in[8];
    const float* lin2  = (const float*)d_in[9];
    const float* lin2b = (const float*)d_in[10];
    float* out = (float*)d_out;

    const int N = in_sizes[0] / HF;
    const int E = in_sizes[2] / 3;

    const size_t fN = (size_t)N * HF;
    float* agg    = (float*)d_ws;                    // N*256 f32
    short* y_p    = (short*)(agg + fN);              // N*256 bf16 (pi-permuted)
    short* x_bf   = y_p + fN;                        // N*256 bf16
    int*   cnt    = (int*)(x_bf + fN);
    int*   row    = cnt + N;                         // N+1
    int*   cursor = row + (N + 8);
    int*   perm   = cursor + N;
    short* w1p    = (short*)(((uintptr_t)(perm + E) + 255) & ~(uintptr_t)255);
    short* w2p    = w1p + 16384;                     // 32 KB / 128 KB
    short* lin1p  = w2p + 65536;
    short* lin2p  = lin1p + 65536;

    hipMemsetAsync(cnt, 0, (size_t)N * sizeof(int), stream);

    const int nx8   = (int)(fN / 8);
    const int nAgg4 = (int)(fN / 4);
    const int gConv = (nx8 + 255) / 256;
    const int gHist = (E + 255) / 256;
    const int gZero = (nAgg4 + 255) / 256;
    prep_kernel<<<dim3(104 + gConv + gHist + gZero), dim3(256), 0, stream>>>(
        w1, b1, w2, lin1, lin2, w1p, w2p, lin1p, lin2p, x, x_bf, nx8,
        eidx, cnt, E, agg, nAgg4, gConv, gHist);

    const int gNode = (N + 31) / 32;
    gemm_scan_kernel<<<dim3(gNode + 1), dim3(256), 0, stream>>>(
        x_bf, lin1p, y_p, N, cnt, row, cursor, E, gNode);

    const int gScatter = (E + 255) / 256;
    scatter_kernel<<<dim3(gScatter), dim3(256), 0, stream>>>(eidx, cursor, perm, E);

    edge_mfma<<<dim3((E + 63) / 64), dim3(256), 0, stream>>>(
        ea, eidx, ew, w1p, w2p, b2, y_p, perm, row, agg, E);

    node2_kernel<<<dim3(gNode), dim3(256), 0, stream>>>(
        agg, lin2p, lin2b, x, out, N);
}

// Round 3
// 357.315 us; speedup vs baseline: 1.1298x; 1.1298x over previous
//
#include <hip/hip_runtime.h>
#include <hip/hip_bf16.h>
#include <stdint.h>

#define HF 256   // H == F == 256
#define GG 50    // G

typedef __attribute__((ext_vector_type(8))) short bf16x8;
typedef __attribute__((ext_vector_type(4))) short bf16x4;
typedef __attribute__((ext_vector_type(4))) float f32x4;
typedef float f32x4a __attribute__((ext_vector_type(4), aligned(4)));  // dword-aligned vec4 load

// packed f32x2 -> bf16x2 (v_cvt_pk_bf16_f32 on gfx950), low short = a
__device__ __forceinline__ uint32_t f2bf2u(float a, float b){
    __hip_bfloat162 h = __float22bfloat162_rn(make_float2(a, b));
    union { __hip_bfloat162 h; uint32_t u; } v; v.h = h; return v.u;
}
__device__ __forceinline__ float bf2f(short s){
    union { uint32_t u; float f; } v; v.u = ((uint32_t)(uint16_t)s) << 16;
    return v.f;
}
// shifted softplus: ln(1+e^x) - ln2 (safe for |x| < ~80; GEMM outputs are O(+-6))
__device__ __forceinline__ float ssp_f(float x){
    float e = __builtin_amdgcn_exp2f(x * 1.44269504088896341f);
    return 0.69314718055994531f * __builtin_amdgcn_logf(1.0f + e)
         - 0.69314718055994531f;
}

// ---------------------------------------------------------------------------
// prep_kernel: [pack weights] + [x fp32->bf16] + [degree histogram] + [agg=0]
// B-frag (ntg, kt): lane l holds B[k=kt*32+(l>>4)*8+j][n=ntg*16+(l&15)].
// pi(s) = (s>>6)*64 + (s&3)*16 + ((s&63)>>2)  (hidden-feature storage perm)
// w1p: bias b1 folded in as constant-1 row k=50 (zero-pad region of K=64).
// ---------------------------------------------------------------------------
__device__ __forceinline__ void pack_natural(const float* __restrict__ B,
                                             short* __restrict__ Bp,
                                             int idx, int KT, int kmax)
{
    int lane = idx & 63;
    int kt   = (idx >> 6) & (KT - 1);
    int ntg  = idx >> (6 + (KT == 2 ? 1 : 3));
    int col  = ntg * 16 + (lane & 15);
    int k0   = kt * 32 + (lane >> 4) * 8;
    uint32_t u[4];
#pragma unroll
    for (int jj = 0; jj < 4; ++jj) {
        int ka = k0 + 2*jj, kb = ka + 1;
        float a = (ka < kmax) ? B[(size_t)ka * HF + col] : 0.f;
        float b = (kb < kmax) ? B[(size_t)kb * HF + col] : 0.f;
        u[jj] = f2bf2u(a, b);
    }
    *(uint4*)&Bp[(size_t)idx * 8] = *(uint4*)u;
}

__global__ __launch_bounds__(256)
void prep_kernel(const float* __restrict__ w1, const float* __restrict__ b1,
                 const float* __restrict__ w2,
                 const float* __restrict__ lin1, const float* __restrict__ lin2,
                 short* __restrict__ w1p, short* __restrict__ w2p,
                 short* __restrict__ lin1p, short* __restrict__ lin2p,
                 const float* __restrict__ x, short* __restrict__ x_bf, int nx8,
                 const int* __restrict__ eidx, int* __restrict__ cnt, int E,
                 float* __restrict__ agg, int nAgg4, int gConv, int gHist)
{
    int b = blockIdx.x, tid = threadIdx.x;
    if (b < 8) {                       // w1p with b1 folded at k==GG
        int idx  = b * 256 + tid;
        int lane = idx & 63;
        int kt   = (idx >> 6) & 1;
        int ntg  = idx >> 7;
        int col  = ntg * 16 + (lane & 15);
        int k0   = kt * 32 + (lane >> 4) * 8;
        uint32_t u[4];
#pragma unroll
        for (int jj = 0; jj < 4; ++jj) {
            int ka = k0 + 2*jj, kb = ka + 1;
            float va = (ka < GG) ? w1[(size_t)ka * HF + col]
                                 : ((ka == GG) ? b1[col] : 0.f);
            float vb = (kb < GG) ? w1[(size_t)kb * HF + col]
                                 : ((kb == GG) ? b1[col] : 0.f);
            u[jj] = f2bf2u(va, vb);
        }
        *(uint4*)&w1p[(size_t)idx * 8] = *(uint4*)u;
    } else if (b < 40) {               // w2p: permuted k axis
        int idx = (b - 8) * 256 + tid;
        int lane = idx & 63;
        int kt   = (idx >> 6) & 7;
        int ntg  = idx >> 9;
        int col  = ntg * 16 + (lane & 15);
        int s0   = kt * 32 + (lane >> 4) * 8;
        uint32_t u[4];
#pragma unroll
        for (int jj = 0; jj < 4; ++jj) {
            int sa = s0 + 2*jj, sb = sa + 1;
            int fa = (sa >> 6) * 64 + (sa & 3) * 16 + ((sa & 63) >> 2);
            int fb = (sb >> 6) * 64 + (sb & 3) * 16 + ((sb & 63) >> 2);
            u[jj] = f2bf2u(w2[(size_t)fa * HF + col], w2[(size_t)fb * HF + col]);
        }
        *(uint4*)&w2p[(size_t)idx * 8] = *(uint4*)u;
    } else if (b < 72) {
        pack_natural(lin1, lin1p, (b - 40) * 256 + tid, 8, HF);
    } else if (b < 104) {
        pack_natural(lin2, lin2p, (b - 72) * 256 + tid, 8, HF);
    } else if (b < 104 + gConv) {      // x -> bf16, 8 elems/thread
        int idx = (b - 104) * 256 + tid;
        if (idx < nx8) {
            const float* xp = x + (size_t)idx * 8;
            float4 p0 = *(const float4*)(xp);
            float4 p1 = *(const float4*)(xp + 4);
            uint32_t u[4] = { f2bf2u(p0.x, p0.y), f2bf2u(p0.z, p0.w),
                              f2bf2u(p1.x, p1.y), f2bf2u(p1.z, p1.w) };
            *(uint4*)&x_bf[(size_t)idx * 8] = *(uint4*)u;
        }
    } else if (b < 104 + gConv + gHist) {   // histogram
        int e = (b - 104 - gConv) * 256 + tid;
        if (e < E) atomicAdd(&cnt[eidx[e]], 1);
    } else {                           // agg zero (float4 granular)
        int idx = (b - 104 - gConv - gHist) * 256 + tid;
        if (idx < nAgg4) ((float4*)agg)[idx] = make_float4(0.f, 0.f, 0.f, 0.f);
    }
}

// ---------------------------------------------------------------------------
// gemm_scan_kernel: blocks [0, gNode) do the y_p GEMM (M-tile 32);
// block gNode runs the 1-block exclusive scan CONCURRENTLY.
// ---------------------------------------------------------------------------
__global__ __launch_bounds__(256)
void gemm_scan_kernel(const short* __restrict__ x_bf, const short* __restrict__ lin1p,
                      short* __restrict__ y_p, int N,
                      const int* __restrict__ cnt, int* __restrict__ row,
                      int* __restrict__ cursor, int E, int gNode)
{
    const int tid = threadIdx.x;
    if ((int)blockIdx.x >= gNode) {    // ---- scan block
        __shared__ int part[256];
        const int CH = (N + 255) / 256;
        int lo = tid * CH;
        int hi = min(lo + CH, N);
        int s = 0;
        for (int n = lo; n < hi; ++n) s += cnt[n];
        part[tid] = s;
        __syncthreads();
        for (int off = 1; off < 256; off <<= 1) {
            int v = (tid >= off) ? part[tid - off] : 0;
            __syncthreads();
            part[tid] += v;
            __syncthreads();
        }
        int acc = part[tid] - s;   // exclusive
        for (int n = lo; n < hi; ++n) {
            row[n] = acc; cursor[n] = acc;
            acc += cnt[n];
        }
        if (tid == 255) row[N] = E;
        return;
    }
    // ---- y_p GEMM
    const int lane = tid & 63;
    const int w    = tid >> 6;
    const int l15  = lane & 15;
    const int quad = lane >> 4;
    const int row0 = blockIdx.x * 32;

    f32x4 acc[2][4];
#pragma unroll
    for (int mt = 0; mt < 2; ++mt)
#pragma unroll
        for (int nt = 0; nt < 4; ++nt) acc[mt][nt] = (f32x4){0.f,0.f,0.f,0.f};

#pragma unroll 2
    for (int kt = 0; kt < 8; ++kt) {
        bf16x8 af[2];
#pragma unroll
        for (int mt = 0; mt < 2; ++mt) {
            int r = row0 + mt * 16 + l15;
            int rl = (r < N) ? r : 0;
            af[mt] = *(const bf16x8*)&x_bf[(size_t)rl * HF + kt * 32 + quad * 8];
        }
#pragma unroll
        for (int nt = 0; nt < 4; ++nt) {
            bf16x8 bfr = *(const bf16x8*)&lin1p[(size_t)(((w*4+nt)*8+kt)*64+lane)*8];
#pragma unroll
            for (int mt = 0; mt < 2; ++mt)
                acc[mt][nt] = __builtin_amdgcn_mfma_f32_16x16x32_bf16(af[mt], bfr, acc[mt][nt], 0, 0, 0);
        }
    }
#pragma unroll
    for (int mt = 0; mt < 2; ++mt) {
#pragma unroll
        for (int r = 0; r < 4; ++r) {
            int row_ = row0 + mt * 16 + quad * 4 + r;
            if (row_ < N) {
                uint2 u = make_uint2(f2bf2u(acc[mt][0][r], acc[mt][1][r]),
                                     f2bf2u(acc[mt][2][r], acc[mt][3][r]));
                *(uint2*)&y_p[(size_t)row_ * HF + w * 64 + l15 * 4] = u;
            }
        }
    }
}

// ---------------------------------------------------------------------------
// scatter_kernel: counting-sort scatter using cursor from the scan
// ---------------------------------------------------------------------------
__global__ __launch_bounds__(256)
void scatter_kernel(const int* __restrict__ eidx, int* __restrict__ cursor,
                    int* __restrict__ perm, int E)
{
    int e = blockIdx.x * 256 + threadIdx.x;
    if (e < E) {
        int pos = atomicAdd(&cursor[eidx[e]], 1);
        perm[pos] = e;
    }
}

// ---------------------------------------------------------------------------
// node2_kernel: out = ssp(agg@lin2 + b) + x   (M-tile 32)
// ---------------------------------------------------------------------------
__global__ __launch_bounds__(256)
void node2_kernel(const float* __restrict__ agg, const short* __restrict__ lin2p,
                  const float* __restrict__ bias, const float* __restrict__ x,
                  float* __restrict__ out, int N)
{
    const int tid  = threadIdx.x;
    const int lane = tid & 63;
    const int w    = tid >> 6;
    const int l15  = lane & 15;
    const int quad = lane >> 4;
    const int row0 = blockIdx.x * 32;

    f32x4 acc[2][4];
#pragma unroll
    for (int mt = 0; mt < 2; ++mt)
#pragma unroll
        for (int nt = 0; nt < 4; ++nt) acc[mt][nt] = (f32x4){0.f,0.f,0.f,0.f};

#pragma unroll 2
    for (int kt = 0; kt < 8; ++kt) {
        bf16x8 af[2];
#pragma unroll
        for (int mt = 0; mt < 2; ++mt) {
            int r = row0 + mt * 16 + l15;
            int rl = (r < N) ? r : 0;
            const float* ap = agg + (size_t)rl * HF + kt * 32 + quad * 8;
            float4 p0 = *(const float4*)(ap);
            float4 p1 = *(const float4*)(ap + 4);
            union { uint32_t u[4]; bf16x8 v; } c;
            c.u[0] = f2bf2u(p0.x, p0.y); c.u[1] = f2bf2u(p0.z, p0.w);
            c.u[2] = f2bf2u(p1.x, p1.y); c.u[3] = f2bf2u(p1.z, p1.w);
            af[mt] = c.v;
        }
#pragma unroll
        for (int nt = 0; nt < 4; ++nt) {
            bf16x8 bfr = *(const bf16x8*)&lin2p[(size_t)(((w*4+nt)*8+kt)*64+lane)*8];
#pragma unroll
            for (int mt = 0; mt < 2; ++mt)
                acc[mt][nt] = __builtin_amdgcn_mfma_f32_16x16x32_bf16(af[mt], bfr, acc[mt][nt], 0, 0, 0);
        }
    }
    float bs[4];
#pragma unroll
    for (int nt = 0; nt < 4; ++nt) bs[nt] = bias[w * 64 + nt * 16 + l15];
#pragma unroll
    for (int mt = 0; mt < 2; ++mt) {
#pragma unroll
        for (int r = 0; r < 4; ++r) {
            int row_ = row0 + mt * 16 + quad * 4 + r;
            if (row_ < N) {
#pragma unroll
                for (int nt = 0; nt < 4; ++nt) {
                    int f = w * 64 + nt * 16 + l15;
                    float v = ssp_f(acc[mt][nt][r] + bs[nt]) + x[(size_t)row_ * HF + f];
                    out[(size_t)row_ * HF + f] = v;
                }
            }
        }
    }
}

// ---------------------------------------------------------------------------
// edge_mfma: per 64-sorted-edge block, 4 waves, wave w owns f-slice [64w,64w+64)
// 3-barrier structure:
//   [no barrier] per-wave metadata (redundant), GEMM1 A direct from fp32 ea
//   (bias row k=50 in-register), GEMM1, y_p gather issue, ssp->hid
//   barA: hid + runnode ready
//   GEMM2 (A from hid LDS, B = w2p)
//   barB: hid dead
//   msg epilogue -> msgT (aliases hid), St build (per-wave ballot mask)
//   barC
//   GEMM3 segment-sum (selection matrix), per-run flush (atomics only at
//   tile-boundary runs)
// LDS 39.2 KB. __launch_bounds__(256,3): the unified VGPR/AGPR file is
// 2048/SIMD; at min-waves=4 the 128-reg cap minus 64 acc-AGPRs left 64 VGPRs
// -> heavy scratch spills (WRITE_SIZE 204 MB, the round-2 regression).
// min-waves=3 gives ~680 regs budget -> no spills, 3 blocks/CU.
// ---------------------------------------------------------------------------
__global__ __launch_bounds__(256, 3)
void edge_mfma(const float* __restrict__ ea, const int* __restrict__ eidx,
               const float* __restrict__ ew,
               const short* __restrict__ w1p,
               const short* __restrict__ w2p, const float* __restrict__ b2,
               const short* __restrict__ y_p, const int* __restrict__ perm,
               const int* __restrict__ rowp,
               float* __restrict__ agg, int E)
{
    __shared__ short smem[19584];      // 39168 B
    short* hid  = smem;                // [64][264] (phase 1-2: 33792 B)
    short* msgT = smem;                // [256][72] (phase 3+, aliases hid)
    short* St   = smem + 18432;        // [16][72]
    __shared__ int s_runnode[64];
    __shared__ unsigned char s_runcomp[64];

    const int tid  = threadIdx.x;
    const int lane = tid & 63;
    const int w    = tid >> 6;
    const int l15  = lane & 15;
    const int quad = lane >> 4;
    const int e0   = blockIdx.x * 64;

    // ---- per-wave metadata: lane holds edge (e0+lane)'s info; no barrier
    int pp = e0 + lane;
    int eL = 0, iv = -1;
    float c = 0.f;
    if (pp < E) {
        eL = perm[pp];
        iv = eidx[eL];
        float d0 = ew[eL*3+0], d1 = ew[eL*3+1], d2 = ew[eL*3+2];
        float d = sqrtf(d0*d0 + d1*d1 + d2*d2);
        c = (d <= 2.0f) ? 0.5f * (__cosf(d * 1.57079632679489662f) + 1.0f) : 0.f;
    }
    int jv = eidx[E + eL];
    int ivn = __shfl_down(iv, 1);
    bool flag = (lane == 63) || (iv != ivn);      // run ends at this lane
    unsigned long long bm = __ballot(flag);       // same value in every wave
    const int runcnt = (int)__popcll(bm);
    if (w == 0 && flag) {
        int rid = (int)__popcll(bm & ((1ull << lane) - 1ull));
        s_runnode[rid] = iv;
        int comp = 0;
        if (iv >= 0) {
            int lo = rowp[iv], hi = rowp[iv + 1];
            comp = (lo >= e0 && hi <= e0 + 64) ? 1 : 0;
        }
        s_runcomp[rid] = (unsigned char)comp;
    }

    // ---- GEMM1 A-fragments: direct dwordx4 loads from fp32 ea + cvt_pk.
    // k layout per fragment: k = kt*32 + quad*8 + j. Row k=50 is the folded
    // bias (constant 1.0), k>50 zero. quad==2/kt==1 covers k=48..55.
    bf16x8 a1[4][2];
#pragma unroll
    for (int mt = 0; mt < 4; ++mt) {
        int rp = __shfl(eL, mt * 16 + l15);       // edge id for A-row
        const float* er = ea + (size_t)rp * GG;
        f32x4a p0 = *(const f32x4a*)(er + quad * 8);
        f32x4a p1 = *(const f32x4a*)(er + quad * 8 + 4);
        union { uint32_t u[4]; bf16x8 v; } ca;
        ca.u[0] = f2bf2u(p0[0], p0[1]); ca.u[1] = f2bf2u(p0[2], p0[3]);
        ca.u[2] = f2bf2u(p1[0], p1[1]); ca.u[3] = f2bf2u(p1[2], p1[3]);
        a1[mt][0] = ca.v;
        union { uint32_t u[4]; bf16x8 v; } cb;
        if (quad < 2) {
            f32x4a q0 = *(const f32x4a*)(er + 32 + quad * 8);
            f32x4a q1 = *(const f32x4a*)(er + 36 + quad * 8);
            cb.u[0] = f2bf2u(q0[0], q0[1]); cb.u[1] = f2bf2u(q0[2], q0[3]);
            cb.u[2] = f2bf2u(q1[0], q1[1]); cb.u[3] = f2bf2u(q1[2], q1[3]);
        } else if (quad == 2) {
            float2 q = *(const float2*)(er + 48);
            cb.u[0] = f2bf2u(q.x, q.y);
            cb.u[1] = 0x00003F80u;      // k=50 -> 1.0 (bias row), k=51 -> 0
            cb.u[2] = 0u; cb.u[3] = 0u;
        } else {
            cb.u[0] = 0u; cb.u[1] = 0u; cb.u[2] = 0u; cb.u[3] = 0u;
        }
        a1[mt][1] = cb.v;
    }

    // ---- GEMM1: [64e x 64k] @ [64k x 64f-slice]
    f32x4 acc1[4][4];
#pragma unroll
    for (int mt = 0; mt < 4; ++mt)
#pragma unroll
        for (int nt = 0; nt < 4; ++nt) acc1[mt][nt] = (f32x4){0.f,0.f,0.f,0.f};
#pragma unroll
    for (int kt = 0; kt < 2; ++kt) {
#pragma unroll
        for (int nt = 0; nt < 4; ++nt) {
            bf16x8 bfr = *(const bf16x8*)&w1p[(size_t)(((w*4+nt)*2+kt)*64+lane)*8];
#pragma unroll
            for (int mt = 0; mt < 4; ++mt)
                acc1[mt][nt] = __builtin_amdgcn_mfma_f32_16x16x32_bf16(a1[mt][kt], bfr, acc1[mt][nt], 0, 0, 0);
        }
    }

    // ---- y_p gather: issue NOW (j via shfl of lane-local jv); consumed after
    // GEMM2 -> latency hides under ssp epilogue + barrier + GEMM2.
    bf16x4 yv[4][4];
#pragma unroll
    for (int mt = 0; mt < 4; ++mt)
#pragma unroll
        for (int r = 0; r < 4; ++r) {
            int j = __shfl(jv, mt * 16 + quad * 4 + r);
            yv[mt][r] = *(const bf16x4*)&y_p[(size_t)j * HF + w * 64 + l15 * 4];
        }

    // ssp -> hid (bf16, col' = w*64 + l15*4 + nt)
#pragma unroll
    for (int mt = 0; mt < 4; ++mt) {
#pragma unroll
        for (int r = 0; r < 4; ++r) {
            int e = mt * 16 + quad * 4 + r;
            float v0 = ssp_f(acc1[mt][0][r]);
            float v1 = ssp_f(acc1[mt][1][r]);
            float v2 = ssp_f(acc1[mt][2][r]);
            float v3 = ssp_f(acc1[mt][3][r]);
            uint2 u = make_uint2(f2bf2u(v0, v1), f2bf2u(v2, v3));
            *(uint2*)&hid[e * 264 + w * 64 + l15 * 4] = u;
        }
    }
    __syncthreads();   // barA: hid + runnode/runcomp ready

    // ---- GEMM2: [64e x 256k(perm)] @ [256k x 64f-slice]
    f32x4 acc2[4][4];
#pragma unroll
    for (int mt = 0; mt < 4; ++mt)
#pragma unroll
        for (int nt = 0; nt < 4; ++nt) acc2[mt][nt] = (f32x4){0.f,0.f,0.f,0.f};

#pragma unroll 2
    for (int kt = 0; kt < 8; ++kt) {
        bf16x8 af[4];
#pragma unroll
        for (int mt = 0; mt < 4; ++mt)
            af[mt] = *(bf16x8*)&hid[(mt * 16 + l15) * 264 + kt * 32 + quad * 8];
#pragma unroll
        for (int nt = 0; nt < 4; ++nt) {
            bf16x8 bfr = *(const bf16x8*)&w2p[(size_t)(((w*4+nt)*8+kt)*64+lane)*8];
#pragma unroll
            for (int mt = 0; mt < 4; ++mt)
                acc2[mt][nt] = __builtin_amdgcn_mfma_f32_16x16x32_bf16(af[mt], bfr, acc2[mt][nt], 0, 0, 0);
        }
    }
    __syncthreads();   // barB: hid dead; msgT/St may now overwrite

    // ---- msg epilogue -> msgT[col][e] (stride 72: 16B-aligned rows)
    float bias2[4];
#pragma unroll
    for (int nt = 0; nt < 4; ++nt) bias2[nt] = b2[w * 64 + nt * 16 + l15];
    float cs[4][4];
#pragma unroll
    for (int mt = 0; mt < 4; ++mt)
#pragma unroll
        for (int r = 0; r < 4; ++r)
            cs[mt][r] = __shfl(c, mt * 16 + quad * 4 + r);
#pragma unroll
    for (int mt = 0; mt < 4; ++mt) {
#pragma unroll
        for (int nt = 0; nt < 4; ++nt) {
            int col = w * 64 + nt * 16 + l15;
            float v0 = (acc2[mt][nt][0] + bias2[nt]) * cs[mt][0] * bf2f(yv[mt][0][nt]);
            float v1 = (acc2[mt][nt][1] + bias2[nt]) * cs[mt][1] * bf2f(yv[mt][1][nt]);
            float v2 = (acc2[mt][nt][2] + bias2[nt]) * cs[mt][2] * bf2f(yv[mt][2][nt]);
            float v3 = (acc2[mt][nt][3] + bias2[nt]) * cs[mt][3] * bf2f(yv[mt][3][nt]);
            uint2 u = make_uint2(f2bf2u(v0, v1), f2bf2u(v2, v3));
            *(uint2*)&msgT[col * 72 + mt * 16 + quad * 4] = u;
        }
    }
    // build S^T[run-local][edge] for run group 0 (stride 72 kills bank conflict)
    {
        int e   = tid & 63;
        int rb  = tid >> 6;
        int rid = (int)__popcll(bm & ((1ull << e) - 1ull));
#pragma unroll
        for (int q = 0; q < 4; ++q) {
            int r = rb + q * 4;
            St[r * 72 + e] = (rid == r) ? (short)0x3F80 : (short)0;
        }
    }
    __syncthreads();   // barC

    // ---- GEMM3: O[feature][run] = msgT @ S^T, then flush per run
    for (int ntg = 0; ntg * 16 < runcnt; ++ntg) {
        if (ntg > 0) {   // rare: >16 runs in a tile
            __syncthreads();
            int e   = tid & 63;
            int rb  = tid >> 6;
            int rid = (int)__popcll(bm & ((1ull << e) - 1ull));
#pragma unroll
            for (int q = 0; q < 4; ++q) {
                int r = rb + q * 4;
                St[r * 72 + e] = (rid == ntg * 16 + r) ? (short)0x3F80 : (short)0;
            }
            __syncthreads();
        }
        f32x4 acc3[4];
#pragma unroll
        for (int mt = 0; mt < 4; ++mt) acc3[mt] = (f32x4){0.f,0.f,0.f,0.f};
#pragma unroll
        for (int kt = 0; kt < 2; ++kt) {
            bf16x8 bS = *(bf16x8*)&St[l15 * 72 + kt * 32 + quad * 8];
#pragma unroll
            for (int mt = 0; mt < 4; ++mt) {
                bf16x8 af = *(bf16x8*)&msgT[(w*64 + mt*16 + l15) * 72 + kt*32 + quad*8];
                acc3[mt] = __builtin_amdgcn_mfma_f32_16x16x32_bf16(af, bS, acc3[mt], 0, 0, 0);
            }
        }
        // lane owns run r = ntg*16 + l15; features f = w*64 + mt*16 + quad*4 + g
        int r = ntg * 16 + l15;
        if (r < runcnt) {
            int node = s_runnode[r];
            if (node >= 0) {
                float* ap = agg + (size_t)node * HF + w * 64 + quad * 4;
                if (s_runcomp[r]) {
#pragma unroll
                    for (int mt = 0; mt < 4; ++mt) {
                        float4 v = make_float4(acc3[mt][0], acc3[mt][1], acc3[mt][2], acc3[mt][3]);
                        *(float4*)(ap + mt * 16) = v;
                    }
                } else {
#pragma unroll
                    for (int mt = 0; mt < 4; ++mt)
#pragma unroll
                        for (int g = 0; g < 4; ++g)
                            atomicAdd(ap + mt * 16 + g, acc3[mt][g]);
                }
            }
        }
    }
}

// ---------------------------------------------------------------------------
extern "C" void kernel_launch(void* const* d_in, const int* in_sizes, int n_in,
                              void* d_out, int out_size, void* d_ws, size_t ws_size,
                              hipStream_t stream)
{
    const float* x     = (const float*)d_in[0];
    const int*   eidx  = (const int*)  d_in[1];
    const float* ew    = (const float*)d_in[2];
    const float* ea    = (const float*)d_in[3];
    const float* w1    = (const float*)d_in[4];
    const float* b1    = (const float*)d_in[5];
    const float* w2    = (const float*)d_in[6];
    const float* b2    = (const float*)d_in[7];
    const float* lin1  = (const float*)d_in[8];
    const float* lin2  = (const float*)d_in[9];
    const float* lin2b = (const float*)d_in[10];
    float* out = (float*)d_out;

    const int N = in_sizes[0] / HF;
    const int E = in_sizes[2] / 3;

    const size_t fN = (size_t)N * HF;
    float* agg    = (float*)d_ws;                    // N*256 f32
    short* y_p    = (short*)(agg + fN);              // N*256 bf16 (pi-permuted)
    short* x_bf   = y_p + fN;                        // N*256 bf16
    int*   cnt    = (int*)(x_bf + fN);
    int*   row    = cnt + N;                         // N+1
    int*   cursor = row + (N + 8);
    int*   perm   = cursor + N;
    short* w1p    = (short*)(((uintptr_t)(perm + E) + 255) & ~(uintptr_t)255);
    short* w2p    = w1p + 16384;                     // 32 KB / 128 KB
    short* lin1p  = w2p + 65536;
    short* lin2p  = lin1p + 65536;

    hipMemsetAsync(cnt, 0, (size_t)N * sizeof(int), stream);

    const int nx8   = (int)(fN / 8);
    const int nAgg4 = (int)(fN / 4);
    const int gConv = (nx8 + 255) / 256;
    const int gHist = (E + 255) / 256;
    const int gZero = (nAgg4 + 255) / 256;
    prep_kernel<<<dim3(104 + gConv + gHist + gZero), dim3(256), 0, stream>>>(
        w1, b1, w2, lin1, lin2, w1p, w2p, lin1p, lin2p, x, x_bf, nx8,
        eidx, cnt, E, agg, nAgg4, gConv, gHist);

    const int gNode = (N + 31) / 32;
    gemm_scan_kernel<<<dim3(gNode + 1), dim3(256), 0, stream>>>(
        x_bf, lin1p, y_p, N, cnt, row, cursor, E, gNode);

    const int gScatter = (E + 255) / 256;
    scatter_kernel<<<dim3(gScatter), dim3(256), 0, stream>>>(eidx, cursor, perm, E);

    edge_mfma<<<dim3((E + 63) / 64), dim3(256), 0, stream>>>(
        ea, eidx, ew, w1p, w2p, b2, y_p, perm, row, agg, E);

    node2_kernel<<<dim3(gNode), dim3(256), 0, stream>>>(
        agg, lin2p, lin2b, x, out, N);
}